// Round 12
// baseline (464.422 us; speedup 1.0000x reference)
//
#include <hip/hip_runtime.h>
#include <hip/hip_bf16.h>

// Problem constants (B=2, S=2048, D=2048, H=16, dk=128)
#define SEQ   2048
#define DIM   2048
#define NH    16
#define DKH   128
#define BATCH 2
#define MROWS (BATCH * SEQ)   // 4096
#define NQT   (SEQ / 64)      // 32 q-tiles per (b,h)

using bf16 = __hip_bfloat16;
typedef __attribute__((ext_vector_type(8))) short short8;
typedef __attribute__((ext_vector_type(4))) short short4v;
typedef __attribute__((ext_vector_type(4))) float floatx4;

union BfBits { bf16 h; short s; };

// async global->LDS, 16 bytes per lane (wave-uniform LDS base + lane*16;
// global source address is per-lane)
__device__ __forceinline__ void gl_lds16(const bf16* g, bf16* l) {
  __builtin_amdgcn_global_load_lds(
      (__attribute__((address_space(1))) void*)(g),
      (__attribute__((address_space(3))) void*)(l), 16, 0, 0);
}

#define S_BAR  __builtin_amdgcn_s_barrier()
#define VMCNT6 do { asm volatile("s_waitcnt vmcnt(6)" ::: "memory"); __builtin_amdgcn_sched_barrier(0); } while (0)
#define VMCNT0 do { asm volatile("s_waitcnt vmcnt(0)" ::: "memory"); __builtin_amdgcn_sched_barrier(0); } while (0)
#define LGKM0  do { asm volatile("s_waitcnt lgkmcnt(0)" ::: "memory"); __builtin_amdgcn_sched_barrier(0); } while (0)

// ---------------- merged cast fp32 -> bf16 for x + 4 weights ----------------
__global__ __launch_bounds__(256) void cast5_kernel(const float* __restrict__ x,
                                                    const float* __restrict__ wq,
                                                    const float* __restrict__ wk,
                                                    const float* __restrict__ wv,
                                                    const float* __restrict__ wo,
                                                    bf16* __restrict__ dst,
                                                    int nX4, int nW4, int nTot) {
  int i = blockIdx.x * 256 + threadIdx.x;
  if (i >= nTot) return;
  const float* src;
  int off;
  int j = i - nX4;
  if (j < 0) { src = x; off = i; }
  else {
    int wsel = j >> 20;          // nW4 = 2^20
    off = j & (nW4 - 1);
    src = (wsel == 0) ? wq : (wsel == 1) ? wk : (wsel == 2) ? wv : wo;
  }
  float4 v = reinterpret_cast<const float4*>(src)[off];
  __hip_bfloat162 h01, h23;
  h01.x = __float2bfloat16(v.x); h01.y = __float2bfloat16(v.y);
  h23.x = __float2bfloat16(v.z); h23.y = __float2bfloat16(v.w);
  reinterpret_cast<__hip_bfloat162*>(dst)[i * 2 + 0] = h01;
  reinterpret_cast<__hip_bfloat162*>(dst)[i * 2 + 1] = h23;
}

// ============ pipelined 256x128 GEMM, BK=64, 3-buffer, 4-phase lockstep ======
// R12: (a) 2D grid again (R11's XCD remap blew per-XCD B working set past L2:
// FETCH 110->213 MB); (b) m201-style per-phase double-barrier schedule:
// per K-tile, 4 phases x { ds_reads, gl_lds issues, S_BAR, lgkm0, setprio1,
// 8 MFMA, setprio0, S_BAR }; vmcnt(6) only at tile end (counted, never 0 in
// steady state).  3-buffer ledger unchanged from R5 (race-screened there):
// buf (kt+2)%3 was consumed at end of kt-1; staged during kt; barriers only
// ADD ordering.  T2-equivalent swizzle (conflicts=0, R4-verified) unchanged.
#define BUFE (256 * 64 + 128 * 64)   // 24576 elems per buffer

// stage one 64-row chunk (1 gl_lds per lane; 1024B per wave)
__device__ __forceinline__ void stage_chunk(const bf16* __restrict__ G, bf16* lds,
                                            int row0, int k0, int w, int l, int u) {
  const int rr = w * 8 + (l >> 3);
  const int cc = ((l & 7) * 8) ^ ((l >> 3) * 8);   // pre-swizzled col (elems)
  gl_lds16(G + (size_t)(row0 + u * 64 + rr) * DIM + k0 + cc,
           lds + (u * 64 + w * 8) * 64);
}

// MODE 0: QKV routing (N=6144). MODE 1: fp32 C via Kout (N=2048).
template <int MODE>
__global__ __launch_bounds__(512, 2) void gemm256(const bf16* __restrict__ A,
                                                  const bf16* __restrict__ Bw,
                                                  bf16* __restrict__ Qraw,
                                                  float* __restrict__ Kout,
                                                  float* __restrict__ Vout) {
  __shared__ bf16 smem[3 * BUFE];  // [buf] { A 256x64 | B 128x64 }

  const int t = threadIdx.x;
  const int w = t >> 6, l = t & 63;
  const int lr = l & 15, quad = l >> 4;
  const int wr = w >> 2;           // 0..1 : row half (128 rows)
  const int wc = w & 3;            // 0..3 : col strip (32 cols)
  const int m0 = blockIdx.y * 256;
  const int n0g = blockIdx.x * 128;

  const int cb = ((quad * 8) ^ ((lr & 7) * 8));  // swizzled k-col base (elems)

  floatx4 acc[8][2];
#pragma unroll
  for (int mi = 0; mi < 8; ++mi)
#pragma unroll
    for (int nj = 0; nj < 2; ++nj) acc[mi][nj] = (floatx4){0.f, 0.f, 0.f, 0.f};

  const int NT = DIM / 64;  // 32 K-tiles

  // prologue: stage tiles 0 and 1 (6 gl_lds per wave each)
#pragma unroll
  for (int u = 0; u < 4; ++u) stage_chunk(A, smem, m0, 0, w, l, u);
#pragma unroll
  for (int u = 0; u < 2; ++u) stage_chunk(Bw, smem + 256 * 64, n0g, 0, w, l, u);
#pragma unroll
  for (int u = 0; u < 4; ++u) stage_chunk(A, smem + BUFE, m0, 64, w, l, u);
#pragma unroll
  for (int u = 0; u < 2; ++u) stage_chunk(Bw, smem + BUFE + 256 * 64, n0g, 64, w, l, u);
  VMCNT6;  // 12 outstanding -> oldest 6 (tile 0) landed
  S_BAR;

  for (int kt = 0; kt < NT; ++kt) {
    const bf16* la = smem + (kt % 3) * BUFE;
    const bf16* lb = la + 256 * 64;
    bf16* stgA = smem + ((kt + 2) % 3) * BUFE;
    bf16* stgB = stgA + 256 * 64;
    const int k2 = (kt + 2) * 64;
    const bool do_stage = (kt + 2 < NT);

    short8 bfr[2][2];
    short8 af[2][2];

    // ---- phase 0: B-frags + A mi{0,1} | stage A chunks 0,1 ----
#pragma unroll
    for (int nj = 0; nj < 2; ++nj) {
      int rb = (wc * 32 + nj * 16 + lr) * 64;
      bfr[nj][0] = *reinterpret_cast<const short8*>(lb + rb + cb);
      bfr[nj][1] = *reinterpret_cast<const short8*>(lb + rb + (cb ^ 32));
    }
#pragma unroll
    for (int i = 0; i < 2; ++i) {
      int ra = (wr * 128 + i * 16 + lr) * 64;
      af[i][0] = *reinterpret_cast<const short8*>(la + ra + cb);
      af[i][1] = *reinterpret_cast<const short8*>(la + ra + (cb ^ 32));
    }
    if (do_stage) { stage_chunk(A, stgA, m0, k2, w, l, 0); stage_chunk(A, stgA, m0, k2, w, l, 1); }
    S_BAR;
    LGKM0;
    __builtin_amdgcn_s_setprio(1);
#pragma unroll
    for (int i = 0; i < 2; ++i)
#pragma unroll
      for (int nj = 0; nj < 2; ++nj) {
        acc[i][nj] = __builtin_amdgcn_mfma_f32_16x16x32_bf16(af[i][0], bfr[nj][0], acc[i][nj], 0, 0, 0);
        acc[i][nj] = __builtin_amdgcn_mfma_f32_16x16x32_bf16(af[i][1], bfr[nj][1], acc[i][nj], 0, 0, 0);
      }
    __builtin_amdgcn_s_setprio(0);
    S_BAR;

    // ---- phase 1: A mi{2,3} | stage A chunks 2,3 ----
#pragma unroll
    for (int i = 0; i < 2; ++i) {
      int ra = (wr * 128 + (i + 2) * 16 + lr) * 64;
      af[i][0] = *reinterpret_cast<const short8*>(la + ra + cb);
      af[i][1] = *reinterpret_cast<const short8*>(la + ra + (cb ^ 32));
    }
    if (do_stage) { stage_chunk(A, stgA, m0, k2, w, l, 2); stage_chunk(A, stgA, m0, k2, w, l, 3); }
    S_BAR;
    LGKM0;
    __builtin_amdgcn_s_setprio(1);
#pragma unroll
    for (int i = 0; i < 2; ++i)
#pragma unroll
      for (int nj = 0; nj < 2; ++nj) {
        acc[i + 2][nj] = __builtin_amdgcn_mfma_f32_16x16x32_bf16(af[i][0], bfr[nj][0], acc[i + 2][nj], 0, 0, 0);
        acc[i + 2][nj] = __builtin_amdgcn_mfma_f32_16x16x32_bf16(af[i][1], bfr[nj][1], acc[i + 2][nj], 0, 0, 0);
      }
    __builtin_amdgcn_s_setprio(0);
    S_BAR;

    // ---- phase 2: A mi{4,5} | stage B chunks 0,1 ----
#pragma unroll
    for (int i = 0; i < 2; ++i) {
      int ra = (wr * 128 + (i + 4) * 16 + lr) * 64;
      af[i][0] = *reinterpret_cast<const short8*>(la + ra + cb);
      af[i][1] = *reinterpret_cast<const short8*>(la + ra + (cb ^ 32));
    }
    if (do_stage) { stage_chunk(Bw, stgB, n0g, k2, w, l, 0); stage_chunk(Bw, stgB, n0g, k2, w, l, 1); }
    S_BAR;
    LGKM0;
    __builtin_amdgcn_s_setprio(1);
#pragma unroll
    for (int i = 0; i < 2; ++i)
#pragma unroll
      for (int nj = 0; nj < 2; ++nj) {
        acc[i + 4][nj] = __builtin_amdgcn_mfma_f32_16x16x32_bf16(af[i][0], bfr[nj][0], acc[i + 4][nj], 0, 0, 0);
        acc[i + 4][nj] = __builtin_amdgcn_mfma_f32_16x16x32_bf16(af[i][1], bfr[nj][1], acc[i + 4][nj], 0, 0, 0);
      }
    __builtin_amdgcn_s_setprio(0);
    S_BAR;

    // ---- phase 3: A mi{6,7} | vmcnt at tile end ----
#pragma unroll
    for (int i = 0; i < 2; ++i) {
      int ra = (wr * 128 + (i + 6) * 16 + lr) * 64;
      af[i][0] = *reinterpret_cast<const short8*>(la + ra + cb);
      af[i][1] = *reinterpret_cast<const short8*>(la + ra + (cb ^ 32));
    }
    S_BAR;
    LGKM0;
    __builtin_amdgcn_s_setprio(1);
#pragma unroll
    for (int i = 0; i < 2; ++i)
#pragma unroll
      for (int nj = 0; nj < 2; ++nj) {
        acc[i + 6][nj] = __builtin_amdgcn_mfma_f32_16x16x32_bf16(af[i][0], bfr[nj][0], acc[i + 6][nj], 0, 0, 0);
        acc[i + 6][nj] = __builtin_amdgcn_mfma_f32_16x16x32_bf16(af[i][1], bfr[nj][1], acc[i + 6][nj], 0, 0, 0);
      }
    __builtin_amdgcn_s_setprio(0);
    if (do_stage) { VMCNT6; } else { VMCNT0; }
    S_BAR;   // publishes buf[kt+1] to all waves
  }

  // epilogue
#pragma unroll
  for (int mi = 0; mi < 8; ++mi)
#pragma unroll
    for (int nj = 0; nj < 2; ++nj) {
      int rg = m0 + wr * 128 + mi * 16 + quad * 4;
      if constexpr (MODE == 0) {
        const int region = n0g >> 11;
        int lcol = (n0g & 2047) + wc * 32 + nj * 16 + lr;
#pragma unroll
        for (int rr2 = 0; rr2 < 4; ++rr2) {
          size_t idx = (size_t)(rg + rr2) * DIM + lcol;
          if (region == 0)      Qraw[idx] = __float2bfloat16(acc[mi][nj][rr2]);
          else if (region == 1) Kout[idx] = acc[mi][nj][rr2];
          else                  Vout[idx] = acc[mi][nj][rr2];
        }
      } else {
        int lcol = n0g + wc * 32 + nj * 16 + lr;
#pragma unroll
        for (int rr2 = 0; rr2 < 4; ++rr2)
          Kout[(size_t)(rg + rr2) * DIM + lcol] = acc[mi][nj][rr2];
      }
    }
}

// ---------------- fused postproc: rope_q | rope_k | V transpose ----------------
#define NRB ((MROWS * DIM / 2) / 256)   // 16384 blocks per rope part

__global__ __launch_bounds__(256) void postproc(const bf16* __restrict__ Qraw,
                                                float* __restrict__ Kf,
                                                const float* __restrict__ cosT,
                                                const float* __restrict__ sinT,
                                                bf16* __restrict__ Qb,
                                                bf16* __restrict__ Kb,
                                                const float* __restrict__ V,
                                                bf16* __restrict__ Vt) {
  int bid = blockIdx.x;
  if (bid < NRB) {
    // ---- rope_q ----
    int g = bid * 256 + threadIdx.x;
    int p = g & 63;
    int r = g >> 6;
    int h = r & 15;
    int s = (r >> 4) & (SEQ - 1);
    int b = r >> 15;
    __hip_bfloat162 v = reinterpret_cast<const __hip_bfloat162*>(Qraw)[g];
    float x0 = __bfloat162float(v.x), x1 = __bfloat162float(v.y);
    float c = cosT[s * 64 + p], sn = sinT[s * 64 + p];
    __hip_bfloat162 o;
    o.x = __float2bfloat16(x0 * c - x1 * sn);
    o.y = __float2bfloat16(x0 * sn + x1 * c);
    reinterpret_cast<__hip_bfloat162*>(Qb)[((size_t)(b * NH + h) * SEQ + s) * 64 + p] = o;
    return;
  }
  bid -= NRB;
  if (bid < NRB) {
    // ---- rope_k ----
    int g = bid * 256 + threadIdx.x;
    int p = g & 63;
    int r = g >> 6;
    int h = r & 15;
    int s = (r >> 4) & (SEQ - 1);
    int b = r >> 15;
    float2 v = reinterpret_cast<const float2*>(Kf)[g];
    float c = cosT[s * 64 + p], sn = sinT[s * 64 + p];
    float o0 = v.x * c - v.y * sn;
    float o1 = v.x * sn + v.y * c;
    reinterpret_cast<float2*>(Kf)[g] = make_float2(o0, o1);
    __hip_bfloat162 ob;
    ob.x = __float2bfloat16(o0);
    ob.y = __float2bfloat16(o1);
    reinterpret_cast<__hip_bfloat162*>(Kb)[((size_t)(b * NH + h) * SEQ + s) * 64 + p] = ob;
    return;
  }
  bid -= NRB;
  {
    // ---- vt : bid in [0, 8192) = (x:64, y:4, z:32) ----
    __shared__ float tile[32][33];
    const int s0 = (bid & 63) * 32;
    const int d0 = ((bid >> 6) & 3) * 32;
    const int bh = bid >> 8;
    const int b = bh >> 4, h = bh & 15;
    const int t = threadIdx.x;
    const int row = t >> 3, c4 = (t & 7) * 4;

    float4 v = *reinterpret_cast<const float4*>(
        V + (size_t)(b * SEQ + s0 + row) * DIM + h * DKH + d0 + c4);
    tile[row][c4 + 0] = v.x; tile[row][c4 + 1] = v.y;
    tile[row][c4 + 2] = v.z; tile[row][c4 + 3] = v.w;
    __syncthreads();

    short4v ov;
#pragma unroll
    for (int i = 0; i < 4; ++i) {
      BfBits u; u.h = __float2bfloat16(tile[c4 + i][row]);
      ov[i] = u.s;
    }
    *reinterpret_cast<short4v*>(Vt + ((size_t)(b * NH + h) * DKH + d0 + row) * SEQ + s0 + c4) = ov;
  }
}

// ---------------- MFMA flash attention (R11 structure, kept) ------------------
__global__ __launch_bounds__(256) void attn_mfma(const bf16* __restrict__ Qb,
                                                 const bf16* __restrict__ Kb,
                                                 const bf16* __restrict__ Vt,
                                                 bf16* __restrict__ ctx) {
  const int orig = blockIdx.x;                     // 0..511
  const int logical = (orig & 7) * 64 + (orig >> 3);  // bijective (512%8==0)
  const int bx = logical & 15;          // q-tile pair
  const int h = (logical >> 4) & 15;    // head
  const int b = logical >> 8;           // batch
  const int t = threadIdx.x;
  const int w = t >> 6, lane = t & 63;
  const int lr = lane & 15, quad = lane >> 4;
  const int kswz = 8 * (lr & 7);   // read-side XOR (frag rows have row&7 == lr&7)

  __shared__ short Ks[2][64 * 128];   // swizzled content, linear layout, 16 KB
  __shared__ short Vs[2][128 * 64];   // swizzled content, linear layout, 16 KB
  __shared__ short Ps[4 * 16 * 72];   // per-wave P strips

  const float scale2 = 0.08838834764831845f * 1.44269504f;  // 1/sqrt(128)*log2e
  const float THR = 11.5413f;      // 8 * log2(e): defer-rescale threshold
  const size_t headQK = (size_t)(b * NH + h) * SEQ * DKH;
  const short* kbase0 = (const short*)Kb + headQK;
  const short* vbase0 = (const short*)Vt + (size_t)(b * NH + h) * DKH * SEQ;

  const int krow_l = w * 4 + (lane >> 4);          // + 16u
  const int kcol_l = ((lane & 15) * 8) ^ (8 * (krow_l & 7));
  const int vrow_l = w * 8 + (lane >> 3);          // + 32u
  const int vcol_l = ((lane & 7) * 8) ^ (8 * (vrow_l & 7));

  auto STAGE = [&](int kt, int buf) {
#pragma unroll
    for (int u = 0; u < 4; ++u) {
      gl_lds16((const bf16*)(kbase0 + (size_t)(kt * 64 + krow_l + 16 * u) * DKH + kcol_l),
               (bf16*)(&Ks[buf][(w * 64 + 256 * u) * 8]));
      gl_lds16((const bf16*)(vbase0 + (size_t)(vrow_l + 32 * u) * SEQ + kt * 64 + vcol_l),
               (bf16*)(&Vs[buf][(w * 64 + 256 * u) * 8]));
    }
  };

  for (int pass = 0; pass < 2; ++pass) {
    const int qt = pass ? bx : (NQT - 1 - bx);

    short8 qa[4];
    {
      const short* qbase = (const short*)Qb + headQK + (size_t)(qt * 64 + w * 16 + lr) * DKH;
#pragma unroll
      for (int kk = 0; kk < 4; ++kk)
        qa[kk] = *reinterpret_cast<const short8*>(qbase + kk * 32 + quad * 8);
    }

    floatx4 o[8];
#pragma unroll
    for (int n = 0; n < 8; ++n) o[n] = (floatx4){0.f, 0.f, 0.f, 0.f};
    float m[4] = {-1e30f, -1e30f, -1e30f, -1e30f};
    float l[4] = {0.f, 0.f, 0.f, 0.f};

    STAGE(0, 0);
    __syncthreads();   // drains vmcnt(0): tile 0 resident

    for (int kt = 0; kt <= qt; ++kt) {
      const int cur = kt & 1;
      if (kt < qt) STAGE(kt + 1, cur ^ 1);   // lands under this iter's compute
      const short* ksb = Ks[cur];
      const short* vsb = Vs[cur];

      floatx4 sj[4];
#pragma unroll
      for (int j = 0; j < 4; ++j) sj[j] = (floatx4){0.f, 0.f, 0.f, 0.f};
#pragma unroll
      for (int j = 0; j < 4; ++j)
#pragma unroll
        for (int kk = 0; kk < 4; ++kk) {
          short8 kb = *reinterpret_cast<const short8*>(
              ksb + (j * 16 + lr) * 128 + ((kk * 32 + quad * 8) ^ kswz));
          sj[j] = __builtin_amdgcn_mfma_f32_16x16x32_bf16(qa[kk], kb, sj[j], 0, 0, 0);
        }

      float sc[4][4];
#pragma unroll
      for (int j = 0; j < 4; ++j)
#pragma unroll
        for (int r = 0; r < 4; ++r) sc[j][r] = sj[j][r] * scale2;
      if (kt == qt) {
#pragma unroll
        for (int j = 0; j < 4; ++j) {
          int col = kt * 64 + j * 16 + lr;
#pragma unroll
          for (int r = 0; r < 4; ++r) {
            int rowg = qt * 64 + w * 16 + quad * 4 + r;
            if (col > rowg) sc[j][r] = -1e9f;
          }
        }
      }

#pragma unroll
      for (int r = 0; r < 4; ++r) {
        float mx = fmaxf(fmaxf(sc[0][r], sc[1][r]), fmaxf(sc[2][r], sc[3][r]));
        mx = fmaxf(mx, __shfl_xor(mx, 1, 16));
        mx = fmaxf(mx, __shfl_xor(mx, 2, 16));
        mx = fmaxf(mx, __shfl_xor(mx, 4, 16));
        mx = fmaxf(mx, __shfl_xor(mx, 8, 16));
        if (!__all(mx - m[r] <= THR)) {
          float mnew = fmaxf(m[r], mx);
          float alpha = __builtin_amdgcn_exp2f(m[r] - mnew);
          l[r] *= alpha;
#pragma unroll
          for (int n = 0; n < 8; ++n) o[n][r] *= alpha;
          m[r] = mnew;
        }
        float rs = 0.f;
#pragma unroll
        for (int j = 0; j < 4; ++j) {
          float p = __builtin_amdgcn_exp2f(sc[j][r] - m[r]);
          rs += p;
          BfBits u; u.h = __float2bfloat16(p);
          Ps[(w * 16 + quad * 4 + r) * 72 + j * 16 + lr] = u.s;
        }
        rs += __shfl_xor(rs, 1, 16);
        rs += __shfl_xor(rs, 2, 16);
        rs += __shfl_xor(rs, 4, 16);
        rs += __shfl_xor(rs, 8, 16);
        l[r] += rs;
      }

      short8 pa0 = *reinterpret_cast<const short8*>(Ps + (w * 16 + lr) * 72 + quad * 8);
      short8 pa1 = *reinterpret_cast<const short8*>(Ps + (w * 16 + lr) * 72 + 32 + quad * 8);
#pragma unroll
      for (int n = 0; n < 8; ++n) {
        short8 vb0 = *reinterpret_cast<const short8*>(
            vsb + (n * 16 + lr) * 64 + ((quad * 8) ^ kswz));
        short8 vb1 = *reinterpret_cast<const short8*>(
            vsb + (n * 16 + lr) * 64 + ((32 + quad * 8) ^ kswz));
        o[n] = __builtin_amdgcn_mfma_f32_16x16x32_bf16(pa0, vb0, o[n], 0, 0, 0);
        o[n] = __builtin_amdgcn_mfma_f32_16x16x32_bf16(pa1, vb1, o[n], 0, 0, 0);
      }
      __syncthreads();  // drains vmcnt (kt+1 staged) + lgkm; publishes buf^1
    }

    float inv[4];
#pragma unroll
    for (int r = 0; r < 4; ++r) inv[r] = 1.0f / l[r];
#pragma unroll
    for (int r = 0; r < 4; ++r) {
      size_t mrow = (size_t)b * SEQ + qt * 64 + w * 16 + quad * 4 + r;
      bf16* dst = ctx + mrow * DIM + h * DKH;
#pragma unroll
      for (int n = 0; n < 8; ++n)
        dst[n * 16 + lr] = __float2bfloat16(o[n][r] * inv[r]);
    }
  }
}

// ---------------- launch ----------------
extern "C" void kernel_launch(void* const* d_in, const int* in_sizes, int n_in,
                              void* d_out, int out_size, void* d_ws, size_t ws_size,
                              hipStream_t stream) {
  const float* x = (const float*)d_in[0];
  const float* fcos = (const float*)d_in[1];
  const float* fsin = (const float*)d_in[2];
  // d_in[3] = mask (causal applied analytically)
  const float* Wq = (const float*)d_in[4];
  const float* Wk = (const float*)d_in[5];
  const float* Wv = (const float*)d_in[6];
  const float* Wo = (const float*)d_in[7];

  float* out = (float*)d_out;                  // M x D
  float* Kout = out + (size_t)MROWS * DIM;     // K cache (fp32, post-RoPE)
  float* Vout = Kout + (size_t)MROWS * DIM;    // V cache (fp32)

  const size_t MD = (size_t)MROWS * DIM;       // 8.39M
  const size_t DD = (size_t)DIM * DIM;         // 4.19M
  bf16* xb   = (bf16*)d_ws;          // MD
  bf16* Wqb  = xb + MD;              // DD x4 (contiguous: fused QKV B-matrix)
  bf16* Wkb  = Wqb + DD;
  bf16* Wvb  = Wkb + DD;
  bf16* Wob  = Wvb + DD;
  bf16* Qraw = Wob + DD;             // MD  (pre-RoPE Q, (B,S,D)); reused as ctxb
  bf16* Qb   = Qraw + MD;            // MD  (post-RoPE, (B,H,S,dk))
  bf16* Kb   = Qb + MD;              // MD  (post-RoPE, (B,H,S,dk))
  bf16* Vt   = Kb + MD;              // MD  ((B,H,dk,S))
  bf16* ctxb = Qraw;                 // alias: Qraw dead after postproc

  const int nXD4 = MROWS * DIM / 4;  // 2^21
  const int nWD4 = DIM * DIM / 4;    // 2^20
  const int nTot = nXD4 + 4 * nWD4;  // 6,291,456
  cast5_kernel<<<nTot / 256, 256, 0, stream>>>(x, Wq, Wk, Wv, Wo, xb, nXD4, nWD4, nTot);

  // fused QKV projection: 2D grid (48,16), 4-phase lockstep schedule
  dim3 gq(3 * DIM / 128, MROWS / 256);
  gemm256<0><<<gq, 512, 0, stream>>>(xb, Wqb, Qraw, Kout, Vout);

  // fused rope_q + rope_k + vt (one launch)
  postproc<<<2 * NRB + 8192, 256, 0, stream>>>(Qraw, Kout, fcos, fsin, Qb, Kb, Vout, Vt);

  // attention: 1D grid 512, XCD-swizzled (4 heads per XCD -> KV L2-resident)
  attn_mfma<<<512, 256, 0, stream>>>(Qb, Kb, Vt, ctxb);

  // output projection: 2D grid (16,16)
  dim3 go(DIM / 128, MROWS / 256);
  gemm256<1><<<go, 512, 0, stream>>>(ctxb, Wob, (bf16*)nullptr, out, (float*)nullptr);
}

// Round 14
// 435.013 us; speedup vs baseline: 1.0676x; 1.0676x over previous
//
#include <hip/hip_runtime.h>
#include <hip/hip_bf16.h>

// Problem constants (B=2, S=2048, D=2048, H=16, dk=128)
#define SEQ   2048
#define DIM   2048
#define NH    16
#define DKH   128
#define BATCH 2
#define MROWS (BATCH * SEQ)   // 4096
#define NQT   (SEQ / 64)      // 32 q-tiles per (b,h)

using bf16 = __hip_bfloat16;
typedef __attribute__((ext_vector_type(8))) short short8;
typedef __attribute__((ext_vector_type(4))) short short4v;
typedef __attribute__((ext_vector_type(4))) float floatx4;

union BfBits { bf16 h; short s; };

// async global->LDS, 16 bytes per lane (wave-uniform LDS base + lane*16;
// global source address is per-lane)
__device__ __forceinline__ void gl_lds16(const bf16* g, bf16* l) {
  __builtin_amdgcn_global_load_lds(
      (__attribute__((address_space(1))) void*)(g),
      (__attribute__((address_space(3))) void*)(l), 16, 0, 0);
}

#define S_BAR  __builtin_amdgcn_s_barrier()
#define VMCNT6 do { asm volatile("s_waitcnt vmcnt(6)" ::: "memory"); __builtin_amdgcn_sched_barrier(0); } while (0)
#define VMCNT0 do { asm volatile("s_waitcnt vmcnt(0)" ::: "memory"); __builtin_amdgcn_sched_barrier(0); } while (0)
#define LGKM0  do { asm volatile("s_waitcnt lgkmcnt(0)" ::: "memory"); __builtin_amdgcn_sched_barrier(0); } while (0)

// ---------------- merged cast fp32 -> bf16 for x + 4 weights ----------------
__global__ __launch_bounds__(256) void cast5_kernel(const float* __restrict__ x,
                                                    const float* __restrict__ wq,
                                                    const float* __restrict__ wk,
                                                    const float* __restrict__ wv,
                                                    const float* __restrict__ wo,
                                                    bf16* __restrict__ dst,
                                                    int nX4, int nW4, int nTot) {
  int i = blockIdx.x * 256 + threadIdx.x;
  if (i >= nTot) return;
  const float* src;
  int off;
  int j = i - nX4;
  if (j < 0) { src = x; off = i; }
  else {
    int wsel = j >> 20;          // nW4 = 2^20
    off = j & (nW4 - 1);
    src = (wsel == 0) ? wq : (wsel == 1) ? wk : (wsel == 2) ? wv : wo;
  }
  float4 v = reinterpret_cast<const float4*>(src)[off];
  __hip_bfloat162 h01, h23;
  h01.x = __float2bfloat16(v.x); h01.y = __float2bfloat16(v.y);
  h23.x = __float2bfloat16(v.z); h23.y = __float2bfloat16(v.w);
  reinterpret_cast<__hip_bfloat162*>(dst)[i * 2 + 0] = h01;
  reinterpret_cast<__hip_bfloat162*>(dst)[i * 2 + 1] = h23;
}

// ============ pipelined 256x128 GEMM, BK=64, 3-buffer, phase-interleaved =====
// R13: EXACT revert to the R5 K-loop (measured 114.8 us, MfmaUtil 39.4%,
// conflicts 0) — R12's per-phase double-barrier (8 bar/tile) cost more than
// the finer interleave gained (130.7 us).  2D grid (R11's XCD remap blew the
// per-XCD B working set past L2: FETCH 110->213 MB).
#define BUFE (256 * 64 + 128 * 64)   // 24576 elems per buffer

template <int ROWS>
__device__ __forceinline__ void stage_swz(const bf16* __restrict__ G, bf16* lds,
                                          int row0, int k0, int w, int l) {
  const int rr = w * 8 + (l >> 3);                 // row within 64-row issue
  const int cc = ((l & 7) * 8) ^ ((l >> 3) * 8);   // pre-swizzled col (elems)
#pragma unroll
  for (int u = 0; u < ROWS / 64; ++u)
    gl_lds16(G + (size_t)(row0 + u * 64 + rr) * DIM + k0 + cc,
             lds + (u * 64 + w * 8) * 64);
}

// MODE 0: QKV routing (N=6144). MODE 1: fp32 C via Kout (N=2048).
template <int MODE>
__global__ __launch_bounds__(512, 2) void gemm256(const bf16* __restrict__ A,
                                                  const bf16* __restrict__ Bw,
                                                  bf16* __restrict__ Qraw,
                                                  float* __restrict__ Kout,
                                                  float* __restrict__ Vout) {
  __shared__ bf16 smem[3 * BUFE];  // [buf] { A 256x64 | B 128x64 }

  const int t = threadIdx.x;
  const int w = t >> 6, l = t & 63;
  const int lr = l & 15, quad = l >> 4;
  const int wr = w >> 2;           // 0..1 : row half (128 rows)
  const int wc = w & 3;            // 0..3 : col strip (32 cols)
  const int m0 = blockIdx.y * 256;
  const int n0g = blockIdx.x * 128;

  const int cb = ((quad * 8) ^ ((lr & 7) * 8));  // swizzled k-col base (elems)

  floatx4 acc[8][2];
#pragma unroll
  for (int mi = 0; mi < 8; ++mi)
#pragma unroll
    for (int nj = 0; nj < 2; ++nj) acc[mi][nj] = (floatx4){0.f, 0.f, 0.f, 0.f};

  const int NT = DIM / 64;  // 32 K-tiles

  // prologue: stage tiles 0 and 1 (6 gl_lds per wave each)
  stage_swz<256>(A, smem, m0, 0, w, l);
  stage_swz<128>(Bw, smem + 256 * 64, n0g, 0, w, l);
  stage_swz<256>(A, smem + BUFE, m0, 64, w, l);
  stage_swz<128>(Bw, smem + BUFE + 256 * 64, n0g, 64, w, l);
  VMCNT6;  // 12 outstanding -> oldest 6 (tile 0) landed
  S_BAR;

  for (int kt = 0; kt < NT; ++kt) {
    const bf16* la = smem + (kt % 3) * BUFE;
    const bf16* lb = la + 256 * 64;
    bf16* stg = smem + ((kt + 2) % 3) * BUFE;
    const bool do_stage = (kt + 2 < NT);

    // ---- phase A: B-frags + A-frags mi 0..3 ----
    short8 bfr[2][2];
#pragma unroll
    for (int nj = 0; nj < 2; ++nj) {
      int rb = (wc * 32 + nj * 16 + lr) * 64;
      bfr[nj][0] = *reinterpret_cast<const short8*>(lb + rb + cb);
      bfr[nj][1] = *reinterpret_cast<const short8*>(lb + rb + (cb ^ 32));
    }
    short8 af[4][2];
#pragma unroll
    for (int i = 0; i < 4; ++i) {
      int ra = (wr * 128 + i * 16 + lr) * 64;
      af[i][0] = *reinterpret_cast<const short8*>(la + ra + cb);
      af[i][1] = *reinterpret_cast<const short8*>(la + ra + (cb ^ 32));
    }
    if (do_stage) stage_swz<256>(A, stg, m0, (kt + 2) * 64, w, l);  // 4 gl_lds
    LGKM0;
    __builtin_amdgcn_s_setprio(1);
#pragma unroll
    for (int i = 0; i < 4; ++i)
#pragma unroll
      for (int nj = 0; nj < 2; ++nj) {
        acc[i][nj] = __builtin_amdgcn_mfma_f32_16x16x32_bf16(
            af[i][0], bfr[nj][0], acc[i][nj], 0, 0, 0);
        acc[i][nj] = __builtin_amdgcn_mfma_f32_16x16x32_bf16(
            af[i][1], bfr[nj][1], acc[i][nj], 0, 0, 0);
      }
    __builtin_amdgcn_s_setprio(0);

    // ---- phase B: A-frags mi 4..7 ----
#pragma unroll
    for (int i = 0; i < 4; ++i) {
      int ra = (wr * 128 + (i + 4) * 16 + lr) * 64;
      af[i][0] = *reinterpret_cast<const short8*>(la + ra + cb);
      af[i][1] = *reinterpret_cast<const short8*>(la + ra + (cb ^ 32));
    }
    if (do_stage) stage_swz<128>(Bw, stg + 256 * 64, n0g, (kt + 2) * 64, w, l);  // 2 gl_lds
    LGKM0;
    __builtin_amdgcn_s_setprio(1);
#pragma unroll
    for (int i = 0; i < 4; ++i)
#pragma unroll
      for (int nj = 0; nj < 2; ++nj) {
        acc[i + 4][nj] = __builtin_amdgcn_mfma_f32_16x16x32_bf16(
            af[i][0], bfr[nj][0], acc[i + 4][nj], 0, 0, 0);
        acc[i + 4][nj] = __builtin_amdgcn_mfma_f32_16x16x32_bf16(
            af[i][1], bfr[nj][1], acc[i + 4][nj], 0, 0, 0);
      }
    __builtin_amdgcn_s_setprio(0);

    // ---- tile end: publish buf[kt+1] ----
    if (do_stage) { VMCNT6; } else { VMCNT0; }
    S_BAR;
  }

  // epilogue
#pragma unroll
  for (int mi = 0; mi < 8; ++mi)
#pragma unroll
    for (int nj = 0; nj < 2; ++nj) {
      int rg = m0 + wr * 128 + mi * 16 + quad * 4;
      if constexpr (MODE == 0) {
        const int region = n0g >> 11;
        int lcol = (n0g & 2047) + wc * 32 + nj * 16 + lr;
#pragma unroll
        for (int rr2 = 0; rr2 < 4; ++rr2) {
          size_t idx = (size_t)(rg + rr2) * DIM + lcol;
          if (region == 0)      Qraw[idx] = __float2bfloat16(acc[mi][nj][rr2]);
          else if (region == 1) Kout[idx] = acc[mi][nj][rr2];
          else                  Vout[idx] = acc[mi][nj][rr2];
        }
      } else {
        int lcol = n0g + wc * 32 + nj * 16 + lr;
#pragma unroll
        for (int rr2 = 0; rr2 < 4; ++rr2)
          Kout[(size_t)(rg + rr2) * DIM + lcol] = acc[mi][nj][rr2];
      }
    }
}

// ---------------- fused postproc: rope_q | rope_k | V transpose ----------------
// R13: ropes vectorized to 16B/lane (G13): each thread handles 4 pairs.
#define NRB8 ((MROWS * DIM / 8) / 256)   // 4096 blocks per rope part

__global__ __launch_bounds__(256) void postproc(const bf16* __restrict__ Qraw,
                                                float* __restrict__ Kf,
                                                const float* __restrict__ cosT,
                                                const float* __restrict__ sinT,
                                                bf16* __restrict__ Qb,
                                                bf16* __restrict__ Kb,
                                                const float* __restrict__ V,
                                                bf16* __restrict__ Vt) {
  int bid = blockIdx.x;
  if (bid < NRB8) {
    // ---- rope_q: 8 elems (4 pairs) per thread ----
    int g = bid * 256 + threadIdx.x;      // < MROWS*DIM/8
    int p4 = (g & 15) * 4;                // first pair index (0..60)
    int r = g >> 4;                       // (b*S+s)*16 + h
    int h = r & 15;
    int s = (r >> 4) & (SEQ - 1);
    int b = r >> 15;
    short8 v = reinterpret_cast<const short8*>(Qraw)[g];
    float4 c4 = *reinterpret_cast<const float4*>(&cosT[s * 64 + p4]);
    float4 s4 = *reinterpret_cast<const float4*>(&sinT[s * 64 + p4]);
    const float* cp = &c4.x;
    const float* sp = &s4.x;
    short8 o;
#pragma unroll
    for (int j = 0; j < 4; ++j) {
      BfBits u0, u1; u0.s = v[2 * j]; u1.s = v[2 * j + 1];
      float x0 = __bfloat162float(u0.h), x1 = __bfloat162float(u1.h);
      BfBits w0, w1;
      w0.h = __float2bfloat16(x0 * cp[j] - x1 * sp[j]);
      w1.h = __float2bfloat16(x0 * sp[j] + x1 * cp[j]);
      o[2 * j] = w0.s; o[2 * j + 1] = w1.s;
    }
    reinterpret_cast<short8*>((short*)Qb)[(((size_t)(b * NH + h) * SEQ + s) * 128 + p4 * 2) / 8] = o;
    return;
  }
  bid -= NRB8;
  if (bid < NRB8) {
    // ---- rope_k: 8 floats (4 pairs) per thread ----
    int g = bid * 256 + threadIdx.x;
    int p4 = (g & 15) * 4;
    int r = g >> 4;
    int h = r & 15;
    int s = (r >> 4) & (SEQ - 1);
    int b = r >> 15;
    float4 va = reinterpret_cast<const float4*>(Kf)[g * 2];
    float4 vb = reinterpret_cast<const float4*>(Kf)[g * 2 + 1];
    float4 c4 = *reinterpret_cast<const float4*>(&cosT[s * 64 + p4]);
    float4 s4 = *reinterpret_cast<const float4*>(&sinT[s * 64 + p4]);
    const float* cp = &c4.x;
    const float* sp = &s4.x;
    float in[8] = {va.x, va.y, va.z, va.w, vb.x, vb.y, vb.z, vb.w};
    float ot[8];
    short8 ob;
#pragma unroll
    for (int j = 0; j < 4; ++j) {
      float x0 = in[2 * j], x1 = in[2 * j + 1];
      ot[2 * j]     = x0 * cp[j] - x1 * sp[j];
      ot[2 * j + 1] = x0 * sp[j] + x1 * cp[j];
      BfBits w0, w1;
      w0.h = __float2bfloat16(ot[2 * j]);
      w1.h = __float2bfloat16(ot[2 * j + 1]);
      ob[2 * j] = w0.s; ob[2 * j + 1] = w1.s;
    }
    reinterpret_cast<float4*>(Kf)[g * 2]     = make_float4(ot[0], ot[1], ot[2], ot[3]);
    reinterpret_cast<float4*>(Kf)[g * 2 + 1] = make_float4(ot[4], ot[5], ot[6], ot[7]);
    reinterpret_cast<short8*>((short*)Kb)[(((size_t)(b * NH + h) * SEQ + s) * 128 + p4 * 2) / 8] = ob;
    return;
  }
  bid -= NRB8;
  {
    // ---- vt : bid in [0, 8192) = (x:64, y:4, z:32) ----
    __shared__ float tile[32][33];
    const int s0 = (bid & 63) * 32;
    const int d0 = ((bid >> 6) & 3) * 32;
    const int bh = bid >> 8;
    const int b = bh >> 4, h = bh & 15;
    const int t = threadIdx.x;
    const int row = t >> 3, c4i = (t & 7) * 4;

    float4 v = *reinterpret_cast<const float4*>(
        V + (size_t)(b * SEQ + s0 + row) * DIM + h * DKH + d0 + c4i);
    tile[row][c4i + 0] = v.x; tile[row][c4i + 1] = v.y;
    tile[row][c4i + 2] = v.z; tile[row][c4i + 3] = v.w;
    __syncthreads();

    short4v ov;
#pragma unroll
    for (int i = 0; i < 4; ++i) {
      BfBits u; u.h = __float2bfloat16(tile[c4i + i][row]);
      ov[i] = u.s;
    }
    *reinterpret_cast<short4v*>(Vt + ((size_t)(b * NH + h) * DKH + d0 + row) * SEQ + s0 + c4i) = ov;
  }
}

// ---------------- MFMA flash attention (R11 structure, kept) ------------------
__global__ __launch_bounds__(256) void attn_mfma(const bf16* __restrict__ Qb,
                                                 const bf16* __restrict__ Kb,
                                                 const bf16* __restrict__ Vt,
                                                 bf16* __restrict__ ctx) {
  const int orig = blockIdx.x;                     // 0..511
  const int logical = (orig & 7) * 64 + (orig >> 3);  // bijective (512%8==0)
  const int bx = logical & 15;          // q-tile pair
  const int h = (logical >> 4) & 15;    // head
  const int b = logical >> 8;           // batch
  const int t = threadIdx.x;
  const int w = t >> 6, lane = t & 63;
  const int lr = lane & 15, quad = lane >> 4;
  const int kswz = 8 * (lr & 7);   // read-side XOR (frag rows have row&7 == lr&7)

  __shared__ short Ks[2][64 * 128];   // swizzled content, linear layout, 16 KB
  __shared__ short Vs[2][128 * 64];   // swizzled content, linear layout, 16 KB
  __shared__ short Ps[4 * 16 * 72];   // per-wave P strips

  const float scale2 = 0.08838834764831845f * 1.44269504f;  // 1/sqrt(128)*log2e
  const float THR = 11.5413f;      // 8 * log2(e): defer-rescale threshold
  const size_t headQK = (size_t)(b * NH + h) * SEQ * DKH;
  const short* kbase0 = (const short*)Kb + headQK;
  const short* vbase0 = (const short*)Vt + (size_t)(b * NH + h) * DKH * SEQ;

  const int krow_l = w * 4 + (lane >> 4);          // + 16u
  const int kcol_l = ((lane & 15) * 8) ^ (8 * (krow_l & 7));
  const int vrow_l = w * 8 + (lane >> 3);          // + 32u
  const int vcol_l = ((lane & 7) * 8) ^ (8 * (vrow_l & 7));

  auto STAGE = [&](int kt, int buf) {
#pragma unroll
    for (int u = 0; u < 4; ++u) {
      gl_lds16((const bf16*)(kbase0 + (size_t)(kt * 64 + krow_l + 16 * u) * DKH + kcol_l),
               (bf16*)(&Ks[buf][(w * 64 + 256 * u) * 8]));
      gl_lds16((const bf16*)(vbase0 + (size_t)(vrow_l + 32 * u) * SEQ + kt * 64 + vcol_l),
               (bf16*)(&Vs[buf][(w * 64 + 256 * u) * 8]));
    }
  };

  for (int pass = 0; pass < 2; ++pass) {
    const int qt = pass ? bx : (NQT - 1 - bx);

    short8 qa[4];
    {
      const short* qbase = (const short*)Qb + headQK + (size_t)(qt * 64 + w * 16 + lr) * DKH;
#pragma unroll
      for (int kk = 0; kk < 4; ++kk)
        qa[kk] = *reinterpret_cast<const short8*>(qbase + kk * 32 + quad * 8);
    }

    floatx4 o[8];
#pragma unroll
    for (int n = 0; n < 8; ++n) o[n] = (floatx4){0.f, 0.f, 0.f, 0.f};
    float m[4] = {-1e30f, -1e30f, -1e30f, -1e30f};
    float l[4] = {0.f, 0.f, 0.f, 0.f};

    STAGE(0, 0);
    __syncthreads();   // drains vmcnt(0): tile 0 resident

    for (int kt = 0; kt <= qt; ++kt) {
      const int cur = kt & 1;
      if (kt < qt) STAGE(kt + 1, cur ^ 1);   // lands under this iter's compute
      const short* ksb = Ks[cur];
      const short* vsb = Vs[cur];

      floatx4 sj[4];
#pragma unroll
      for (int j = 0; j < 4; ++j) sj[j] = (floatx4){0.f, 0.f, 0.f, 0.f};
#pragma unroll
      for (int j = 0; j < 4; ++j)
#pragma unroll
        for (int kk = 0; kk < 4; ++kk) {
          short8 kb = *reinterpret_cast<const short8*>(
              ksb + (j * 16 + lr) * 128 + ((kk * 32 + quad * 8) ^ kswz));
          sj[j] = __builtin_amdgcn_mfma_f32_16x16x32_bf16(qa[kk], kb, sj[j], 0, 0, 0);
        }

      float sc[4][4];
#pragma unroll
      for (int j = 0; j < 4; ++j)
#pragma unroll
        for (int r = 0; r < 4; ++r) sc[j][r] = sj[j][r] * scale2;
      if (kt == qt) {
#pragma unroll
        for (int j = 0; j < 4; ++j) {
          int col = kt * 64 + j * 16 + lr;
#pragma unroll
          for (int r = 0; r < 4; ++r) {
            int rowg = qt * 64 + w * 16 + quad * 4 + r;
            if (col > rowg) sc[j][r] = -1e9f;
          }
        }
      }

#pragma unroll
      for (int r = 0; r < 4; ++r) {
        float mx = fmaxf(fmaxf(sc[0][r], sc[1][r]), fmaxf(sc[2][r], sc[3][r]));
        mx = fmaxf(mx, __shfl_xor(mx, 1, 16));
        mx = fmaxf(mx, __shfl_xor(mx, 2, 16));
        mx = fmaxf(mx, __shfl_xor(mx, 4, 16));
        mx = fmaxf(mx, __shfl_xor(mx, 8, 16));
        if (!__all(mx - m[r] <= THR)) {
          float mnew = fmaxf(m[r], mx);
          float alpha = __builtin_amdgcn_exp2f(m[r] - mnew);
          l[r] *= alpha;
#pragma unroll
          for (int n = 0; n < 8; ++n) o[n][r] *= alpha;
          m[r] = mnew;
        }
        float rs = 0.f;
#pragma unroll
        for (int j = 0; j < 4; ++j) {
          float p = __builtin_amdgcn_exp2f(sc[j][r] - m[r]);
          rs += p;
          BfBits u; u.h = __float2bfloat16(p);
          Ps[(w * 16 + quad * 4 + r) * 72 + j * 16 + lr] = u.s;
        }
        rs += __shfl_xor(rs, 1, 16);
        rs += __shfl_xor(rs, 2, 16);
        rs += __shfl_xor(rs, 4, 16);
        rs += __shfl_xor(rs, 8, 16);
        l[r] += rs;
      }

      short8 pa0 = *reinterpret_cast<const short8*>(Ps + (w * 16 + lr) * 72 + quad * 8);
      short8 pa1 = *reinterpret_cast<const short8*>(Ps + (w * 16 + lr) * 72 + 32 + quad * 8);
#pragma unroll
      for (int n = 0; n < 8; ++n) {
        short8 vb0 = *reinterpret_cast<const short8*>(
            vsb + (n * 16 + lr) * 64 + ((quad * 8) ^ kswz));
        short8 vb1 = *reinterpret_cast<const short8*>(
            vsb + (n * 16 + lr) * 64 + ((32 + quad * 8) ^ kswz));
        o[n] = __builtin_amdgcn_mfma_f32_16x16x32_bf16(pa0, vb0, o[n], 0, 0, 0);
        o[n] = __builtin_amdgcn_mfma_f32_16x16x32_bf16(pa1, vb1, o[n], 0, 0, 0);
      }
      __syncthreads();  // drains vmcnt (kt+1 staged) + lgkm; publishes buf^1
    }

    float inv[4];
#pragma unroll
    for (int r = 0; r < 4; ++r) inv[r] = 1.0f / l[r];
#pragma unroll
    for (int r = 0; r < 4; ++r) {
      size_t mrow = (size_t)b * SEQ + qt * 64 + w * 16 + quad * 4 + r;
      bf16* dst = ctx + mrow * DIM + h * DKH;
#pragma unroll
      for (int n = 0; n < 8; ++n)
        dst[n * 16 + lr] = __float2bfloat16(o[n][r] * inv[r]);
    }
  }
}

// ---------------- launch ----------------
extern "C" void kernel_launch(void* const* d_in, const int* in_sizes, int n_in,
                              void* d_out, int out_size, void* d_ws, size_t ws_size,
                              hipStream_t stream) {
  const float* x = (const float*)d_in[0];
  const float* fcos = (const float*)d_in[1];
  const float* fsin = (const float*)d_in[2];
  // d_in[3] = mask (causal applied analytically)
  const float* Wq = (const float*)d_in[4];
  const float* Wk = (const float*)d_in[5];
  const float* Wv = (const float*)d_in[6];
  const float* Wo = (const float*)d_in[7];

  float* out = (float*)d_out;                  // M x D
  float* Kout = out + (size_t)MROWS * DIM;     // K cache (fp32, post-RoPE)
  float* Vout = Kout + (size_t)MROWS * DIM;    // V cache (fp32)

  const size_t MD = (size_t)MROWS * DIM;       // 8.39M
  const size_t DD = (size_t)DIM * DIM;         // 4.19M
  bf16* xb   = (bf16*)d_ws;          // MD
  bf16* Wqb  = xb + MD;              // DD x4 (contiguous: fused QKV B-matrix)
  bf16* Wkb  = Wqb + DD;
  bf16* Wvb  = Wkb + DD;
  bf16* Wob  = Wvb + DD;
  bf16* Qraw = Wob + DD;             // MD  (pre-RoPE Q, (B,S,D)); reused as ctxb
  bf16* Qb   = Qraw + MD;            // MD  (post-RoPE, (B,H,S,dk))
  bf16* Kb   = Qb + MD;              // MD  (post-RoPE, (B,H,S,dk))
  bf16* Vt   = Kb + MD;              // MD  ((B,H,dk,S))
  bf16* ctxb = Qraw;                 // alias: Qraw dead after postproc

  const int nXD4 = MROWS * DIM / 4;  // 2^21
  const int nWD4 = DIM * DIM / 4;    // 2^20
  const int nTot = nXD4 + 4 * nWD4;  // 6,291,456
  cast5_kernel<<<nTot / 256, 256, 0, stream>>>(x, Wq, Wk, Wv, Wo, xb, nXD4, nWD4, nTot);

  // fused QKV projection: 2D grid (48,16), R5 schedule
  dim3 gq(3 * DIM / 128, MROWS / 256);
  gemm256<0><<<gq, 512, 0, stream>>>(xb, Wqb, Qraw, Kout, Vout);

  // fused rope_q + rope_k + vt (one launch, 16B/lane ropes)
  postproc<<<2 * NRB8 + 8192, 256, 0, stream>>>(Qraw, Kout, fcos, fsin, Qb, Kb, Vout, Vt);

  // attention: 1D grid 512, XCD-swizzled (4 heads per XCD -> KV L2-resident)
  attn_mfma<<<512, 256, 0, stream>>>(Qb, Kb, Vt, ctxb);

  // output projection: 2D grid (16,16), R5 schedule
  dim3 go(DIM / 128, MROWS / 256);
  gemm256<1><<<go, 512, 0, stream>>>(ctxb, Wob, (bf16*)nullptr, out, (float*)nullptr);
}